// Round 4
// baseline (458.030 us; speedup 1.0000x reference)
//
#include <hip/hip_runtime.h>
#include <stdint.h>

typedef _Float16 half8 __attribute__((ext_vector_type(8)));
typedef _Float16 half4v __attribute__((ext_vector_type(4)));
typedef float floatx4 __attribute__((ext_vector_type(4)));
typedef float floatx16 __attribute__((ext_vector_type(16)));

#define TT 4096
#define DH 512

#define WAITVM(n) asm volatile("s_waitcnt vmcnt(" #n ")" ::: "memory")
#define WAITLGKM() asm volatile("s_waitcnt lgkmcnt(0)" ::: "memory")
#define BAR() __builtin_amdgcn_s_barrier()

__device__ __forceinline__ unsigned short f2h(float f) {
    union { _Float16 h; unsigned short u; } v;
    v.h = (_Float16)f;
    return v.u;
}

// ---------- kernel 1: normalize right half of x -> xn (fp16), one wave per row ----------
__global__ void norm_k(const float* __restrict__ x, unsigned short* __restrict__ xn) {
    const int w = threadIdx.x >> 6, l = threadIdx.x & 63;
    const int row = blockIdx.x * 4 + w;              // 0 .. B*T-1
    const float* src = x + (size_t)row * 1024 + 512 + l * 8;
    floatx4 a = *(const floatx4*)src;
    floatx4 c = *(const floatx4*)(src + 4);
    float s = a[0]*a[0] + a[1]*a[1] + a[2]*a[2] + a[3]*a[3]
            + c[0]*c[0] + c[1]*c[1] + c[2]*c[2] + c[3]*c[3];
    #pragma unroll
    for (int off = 32; off > 0; off >>= 1) s += __shfl_xor(s, off);
    const float scale = 1.0f / fmaxf(sqrtf(s), 1e-12f);
    float v[8] = {a[0], a[1], a[2], a[3], c[0], c[1], c[2], c[3]};
    uint32_t pk[4];
    #pragma unroll
    for (int i = 0; i < 4; i++)
        pk[i] = (uint32_t)f2h(v[2*i] * scale) | ((uint32_t)f2h(v[2*i+1] * scale) << 16);
    uint4 o; o.x = pk[0]; o.y = pk[1]; o.z = pk[2]; o.w = pk[3];
    *(uint4*)(xn + (size_t)row * DH + l * 8) = o;
}

// ---------- kernel 2: xnT[b][d][t] = xn[b][t][d], 64x64 LDS tile transpose ----------
__global__ void transpose_k(const unsigned short* __restrict__ xn,
                            unsigned short* __restrict__ xnT) {
    __shared__ __align__(16) unsigned short tile[64 * 72];  // +8 pad
    const int b = blockIdx.z;
    const int t0 = blockIdx.x * 64, d0 = blockIdx.y * 64;
    const int tid = threadIdx.x;
    #pragma unroll
    for (int i = 0; i < 2; i++) {
        int c = i * 256 + tid;
        int tr = c >> 3, d8 = c & 7;
        uint4 vv = *(const uint4*)(xn + ((size_t)(b * TT + t0 + tr) * DH + d0 + d8 * 8));
        *(uint4*)&tile[tr * 72 + d8 * 8] = vv;
    }
    __syncthreads();
    #pragma unroll
    for (int i = 0; i < 2; i++) {
        int c = i * 256 + tid;
        int dd = c >> 3, t8 = c & 7;
        uint32_t pk[4];
        #pragma unroll
        for (int k = 0; k < 4; k++) {
            uint32_t h0 = tile[(t8 * 8 + 2 * k    ) * 72 + dd];
            uint32_t h1 = tile[(t8 * 8 + 2 * k + 1) * 72 + dd];
            pk[k] = h0 | (h1 << 16);
        }
        uint4 o; o.x = pk[0]; o.y = pk[1]; o.z = pk[2]; o.w = pk[3];
        *(uint4*)(xnT + ((size_t)(b * DH + d0 + dd) * TT + t0 + t8 * 8)) = o;
    }
}

// ---------- kernel 3: wave-specialized fused kernel ----------
// 512 threads = 8 waves; 2 barriers per tile-phase (barA, barB). 65 phases.
// S-group (waves 0-3, role mi=w&1, dh=w>>1):
//   slot1 (barA..barB): S^T[mi-half kk][64 q] partial over dh-half of K.
//     16 A-reads from knL, each feeds 2 mfma (ni=0,1). Writes Sred[dh].
//   slot2 (barB..barA): reduce 2 partials for q-rows w*16..+16, *V, write W[t&1];
//     then restage knL[t+1] (safe: all s1 reads done at barB) + prefetch V[t+1].
// C-group (waves 4-7, d-slice (w-4)*128..+128): at phase t does s3 for tile t-1:
//   issues kt[t-1] register loads at barA (land during S slot1), reads W[(t-1)&1],
//   32 mfma into persistent acc.
__global__ __launch_bounds__(512, 2) void fused_k(
    const unsigned short* __restrict__ xn, const unsigned short* __restrict__ xnT,
    const float* __restrict__ V, const float* __restrict__ bias,
    const float* __restrict__ x, float* __restrict__ out)
{
    __shared__ __align__(16) unsigned short smem[50688];   // 99 KiB
    unsigned short* knL   = smem;            // [64 kk][512 d], chunk16 ^ (kk&7)
    unsigned short* SredL = smem + 32768;    // [2 dh][64 q][64 kk], unit4 ^ ((q&7)<<1)
    unsigned short* Wl    = smem + 40960;    // [2 buf][64 q][76]

    const int tid = threadIdx.x;
    const int w = tid >> 6, l = tid & 63;
    const int h = l >> 5, m32 = l & 31;

    // XCD-aware swizzle
    const int flat = blockIdx.y * 64 + blockIdx.x;
    const int work = (flat & 7) * 32 + (flat >> 3);
    const int b = work >> 6, qt = work & 63;
    const int q0 = qt * 64;

    const unsigned short* xnb = xn  + (size_t)b * TT * DH;
    const unsigned short* xtb = xnT + (size_t)b * DH * TT;

    if (w < 4) {
        // ================= S-group =================
        const int mi = w & 1, dh = w >> 1;
        const int qh = l & 15, kc = l >> 4;          // slot2 mapping
        const int q2 = q0 + w * 16 + qh;
        const float* vptr = V + (size_t)q2 * TT + kc * 16;

        // Q fragments: B-operand, lane q = q0+ni*32+m32, k = dh*256+ks*16+h*8+j
        half8 qf[2][16];
        #pragma unroll
        for (int ni = 0; ni < 2; ni++)
            #pragma unroll
            for (int ks = 0; ks < 16; ks++)
                qf[ni][ks] = *(const half8*)(xnb + (size_t)(q0 + ni*32 + m32) * DH
                                             + dh*256 + ks*16 + h*8);
        asm volatile("" ::: "memory");
        // stage kn[0]: wave w stages rows w*16..+15
        #pragma unroll
        for (int i = 0; i < 16; i++) {
            int r = w * 16 + i;
            const unsigned short* g = xnb + (size_t)r * DH + ((l ^ (r & 7)) * 8);
            __builtin_amdgcn_global_load_lds(
                (const __attribute__((address_space(1))) void*)g,
                (__attribute__((address_space(3))) void*)&knL[r * 512], 16, 0, 0);
        }
        asm volatile("" ::: "memory");
        floatx4 vf0 = *(const floatx4*)(vptr + 0);
        floatx4 vf1 = *(const floatx4*)(vptr + 4);
        floatx4 vf2 = *(const floatx4*)(vptr + 8);
        floatx4 vf3 = *(const floatx4*)(vptr + 12);

        const int arow = mi * 32 + m32;
        const unsigned short* ab = knL + arow * 512;
        const int ax = arow & 7;
        const int qsw = (qh & 7) << 1;
        const unsigned short* s0p = SredL + (size_t)(w*16 + qh) * 64;
        const unsigned short* s1p = s0p + 4096;

        #pragma unroll 1
        for (int t = 0; t < 65; t++) {
            if (t < 64) {
                WAITVM(4);           // kn[t] landed (V prefetch may still fly)
                BAR();               // barA
                // ---- slot1: s1 ----
                floatx16 sa = (floatx16)(0.f), sb = (floatx16)(0.f);
                __builtin_amdgcn_s_setprio(1);
                #pragma unroll
                for (int ks = 0; ks < 16; ks++) {
                    half8 a = *(const half8*)&ab[((dh*16 + ks*2 + h) ^ ax) * 8];
                    sa = __builtin_amdgcn_mfma_f32_32x32x16_f16(a, qf[0][ks], sa, 0, 0, 0);
                    sb = __builtin_amdgcn_mfma_f32_32x32x16_f16(a, qf[1][ks], sb, 0, 0, 0);
                }
                __builtin_amdgcn_s_setprio(0);
                // Sred write: q = ni*32+m32, unit kk4 = mi*8+rr*2+h, ^ ((q&7)<<1)
                #pragma unroll
                for (int ni = 0; ni < 2; ni++) {
                    const int q = ni * 32 + m32;
                    const int sw = (q & 7) << 1;
                    unsigned short* sp = SredL + dh * 4096 + q * 64;
                    #pragma unroll
                    for (int rr = 0; rr < 4; rr++) {
                        int u = (mi*8 + rr*2 + h) ^ sw;
                        half4v v4;
                        if (ni == 0) {
                            v4[0]=(_Float16)sa[rr*4+0]; v4[1]=(_Float16)sa[rr*4+1];
                            v4[2]=(_Float16)sa[rr*4+2]; v4[3]=(_Float16)sa[rr*4+3];
                        } else {
                            v4[0]=(_Float16)sb[rr*4+0]; v4[1]=(_Float16)sb[rr*4+1];
                            v4[2]=(_Float16)sb[rr*4+2]; v4[3]=(_Float16)sb[rr*4+3];
                        }
                        *(half4v*)&sp[u * 4] = v4;
                    }
                }
                WAITLGKM();
                BAR();               // barB
                // ---- slot2: reduce + *V + W write ----
                float s16[16];
                #pragma unroll
                for (int i = 0; i < 4; i++) {
                    int u = ((kc*4 + i) ^ qsw) * 4;
                    half4v p0 = *(const half4v*)&s0p[u];
                    half4v p1 = *(const half4v*)&s1p[u];
                    #pragma unroll
                    for (int j = 0; j < 4; j++) s16[i*4+j] = (float)p0[j] + (float)p1[j];
                }
                WAITVM(0);           // V[t] landed (kn[t+1] not yet issued)
                half8 wlo, whi;
                wlo[0]=(_Float16)(s16[0]*vf0[0]);  wlo[1]=(_Float16)(s16[1]*vf0[1]);
                wlo[2]=(_Float16)(s16[2]*vf0[2]);  wlo[3]=(_Float16)(s16[3]*vf0[3]);
                wlo[4]=(_Float16)(s16[4]*vf1[0]);  wlo[5]=(_Float16)(s16[5]*vf1[1]);
                wlo[6]=(_Float16)(s16[6]*vf1[2]);  wlo[7]=(_Float16)(s16[7]*vf1[3]);
                whi[0]=(_Float16)(s16[8]*vf2[0]);  whi[1]=(_Float16)(s16[9]*vf2[1]);
                whi[2]=(_Float16)(s16[10]*vf2[2]); whi[3]=(_Float16)(s16[11]*vf2[3]);
                whi[4]=(_Float16)(s16[12]*vf3[0]); whi[5]=(_Float16)(s16[13]*vf3[1]);
                whi[6]=(_Float16)(s16[14]*vf3[2]); whi[7]=(_Float16)(s16[15]*vf3[3]);
                unsigned short* wp = Wl + (t & 1) * 4864 + (size_t)(w*16 + qh) * 76 + kc * 16;
                *(half8*)&wp[0] = wlo;
                *(half8*)&wp[8] = whi;
                WAITLGKM();          // W writes + Sred reads drained before next barA
                // ---- restage kn[t+1] + prefetch V[t+1] ----
                if (t < 63) {
                    #pragma unroll
                    for (int i = 0; i < 16; i++) {
                        int r = w * 16 + i;
                        const unsigned short* g = xnb + (size_t)((t+1)*64 + r) * DH
                                                  + ((l ^ (r & 7)) * 8);
                        __builtin_amdgcn_global_load_lds(
                            (const __attribute__((address_space(1))) void*)g,
                            (__attribute__((address_space(3))) void*)&knL[r * 512], 16, 0, 0);
                    }
                    asm volatile("" ::: "memory");
                    vf0 = *(const floatx4*)(vptr + (t+1)*64 + 0);
                    vf1 = *(const floatx4*)(vptr + (t+1)*64 + 4);
                    vf2 = *(const floatx4*)(vptr + (t+1)*64 + 8);
                    vf3 = *(const floatx4*)(vptr + (t+1)*64 + 12);
                }
            } else {
                BAR(); BAR();
            }
        }
        // S-group: no epilogue
    } else {
        // ================= C-group =================
        const int cw = w - 4;
        const int db = cw * 128;
        floatx16 acc[2][4];
        #pragma unroll
        for (int i = 0; i < 2; i++)
            #pragma unroll
            for (int j = 0; j < 4; j++)
                acc[i][j] = (floatx16)(0.f);
        half8 bf[4][4];

        #pragma unroll 1
        for (int t = 0; t < 65; t++) {
            if (t >= 1) {
                BAR();               // barA: W[t-1] complete, kt[t-1] cols valid
                // issue kt[t-1] register loads (land during S slot1)
                #pragma unroll
                for (int nd = 0; nd < 4; nd++)
                    #pragma unroll
                    for (int ks = 0; ks < 4; ks++)
                        bf[nd][ks] = *(const half8*)(xtb + (size_t)(db + nd*32 + m32) * TT
                                                     + (t-1)*64 + ks*16 + h*8);
                BAR();               // barB (matches S's; nothing gated for C)
                WAITVM(0);
                const unsigned short* wb = Wl + ((t-1) & 1) * 4864;
                __builtin_amdgcn_s_setprio(1);
                #pragma unroll
                for (int ks = 0; ks < 4; ks++) {
                    half8 wf0 = *(const half8*)&wb[(size_t)(m32     ) * 76 + ks*16 + h*8];
                    half8 wf1 = *(const half8*)&wb[(size_t)(32 + m32) * 76 + ks*16 + h*8];
                    acc[0][0] = __builtin_amdgcn_mfma_f32_32x32x16_f16(wf0, bf[0][ks], acc[0][0], 0, 0, 0);
                    acc[0][1] = __builtin_amdgcn_mfma_f32_32x32x16_f16(wf0, bf[1][ks], acc[0][1], 0, 0, 0);
                    acc[0][2] = __builtin_amdgcn_mfma_f32_32x32x16_f16(wf0, bf[2][ks], acc[0][2], 0, 0, 0);
                    acc[0][3] = __builtin_amdgcn_mfma_f32_32x32x16_f16(wf0, bf[3][ks], acc[0][3], 0, 0, 0);
                    acc[1][0] = __builtin_amdgcn_mfma_f32_32x32x16_f16(wf1, bf[0][ks], acc[1][0], 0, 0, 0);
                    acc[1][1] = __builtin_amdgcn_mfma_f32_32x32x16_f16(wf1, bf[1][ks], acc[1][1], 0, 0, 0);
                    acc[1][2] = __builtin_amdgcn_mfma_f32_32x32x16_f16(wf1, bf[2][ks], acc[1][2], 0, 0, 0);
                    acc[1][3] = __builtin_amdgcn_mfma_f32_32x32x16_f16(wf1, bf[3][ks], acc[1][3], 0, 0, 0);
                }
                __builtin_amdgcn_s_setprio(0);
            } else {
                BAR(); BAR();
            }
        }
        // ---- epilogue ----
        const float* xb = x + (size_t)b * TT * 1024;
        float* ob = out + (size_t)b * TT * DH;
        #pragma unroll
        for (int mi2 = 0; mi2 < 2; mi2++)
            #pragma unroll
            for (int nd = 0; nd < 4; nd++) {
                int d = db + nd * 32 + m32;
                float bv = bias[d];
                #pragma unroll
                for (int r = 0; r < 16; r++) {
                    int q = q0 + mi2 * 32 + (r & 3) + 8 * (r >> 2) + 4 * h;
                    float cv = acc[mi2][nd][r] + bv;
                    float gate = 1.0f / (1.0f + __expf(-cv));
                    ob[(size_t)q * DH + d] = xb[(size_t)q * 1024 + d] * gate;
                }
            }
    }
}

extern "C" void kernel_launch(void* const* d_in, const int* in_sizes, int n_in,
                              void* d_out, int out_size, void* d_ws, size_t ws_size,
                              hipStream_t stream) {
    const float* x    = (const float*)d_in[0];
    const float* V    = (const float*)d_in[1];
    const float* bias = (const float*)d_in[2];
    float* out = (float*)d_out;

    unsigned short* xn  = (unsigned short*)d_ws;              // [4][4096][512] fp16
    unsigned short* xnT = xn + (size_t)4 * TT * DH;           // [4][512][4096] fp16

    norm_k<<<dim3(4 * TT / 4), 256, 0, stream>>>(x, xn);
    transpose_k<<<dim3(TT / 64, DH / 64, 4), 256, 0, stream>>>(xn, xnT);
    fused_k<<<dim3(TT / 64, 4), 512, 0, stream>>>(xn, xnT, V, bias, x, out);
}